// Round 1
// baseline (295.425 us; speedup 1.0000x reference)
//
#include <hip/hip_runtime.h>
#include <cstdint>
#include <cstddef>

// ---- problem constants ----
#define SEQLEN 2048
#define NBATCH 2
#define NIND   256
#define NPOS   256
#define NCIN   512   // NIND + NPOS
#define NH     8
#define NDE    64
#define NDV    64
#define NREC   64
#define WINW   192   // 64 + 2*NREC
#define KPITCH 196   // K tile pitch (row-major [d][c])
#define VPITCH 68    // V^T / P^T pitch (row-major [c][d] / [c][r])
#define QPITCH 68

// ---------------- positional embedding ----------------
// Must match JAX fp32 chain bitwise-ish: base=float(1.2), w=0.8f+float(1.2f^k),
// swl=2048f/w, arg=(f32(2pi)*l)/swl, then sinf/cosf (exact range reduction).
__global__ __launch_bounds__(256) void pos_k(float* __restrict__ pos) {
  int j = blockIdx.x;                       // 0..255
  int i = (j < NPOS / 2) ? j : j - NPOS / 2;
  const double base = (double)1.2f;         // JAX weak-types 1.2 to f32 first
  double p = 1.0;
  for (int tt = 0; tt <= i; ++tt) p *= base;   // (1.2f)^(i+1) in double
  float w = 0.8f + (float)p;
  float swl = (float)SEQLEN / w;
  const float two_pi = (float)(2.0 * 3.14159265358979323846);
  for (int l = threadIdx.x; l < SEQLEN; l += blockDim.x) {
    float arg = (two_pi * (float)l) / swl;
    pos[(size_t)j * SEQLEN + l] = (j < NPOS / 2) ? sinf(arg) : cosf(arg);
  }
}

// ---------------- concat x & pos -> xp (B, 512, L) ----------------
__global__ __launch_bounds__(256) void concat_k(const float* __restrict__ x,
                                                const float* __restrict__ pos,
                                                float* __restrict__ xp) {
  int idx = blockIdx.x * 256 + threadIdx.x;        // < 2*512*2048 = 2^21
  int l = idx & (SEQLEN - 1);
  int c = (idx >> 11) & (NCIN - 1);
  int b = idx >> 20;
  xp[idx] = (c < NIND) ? x[((size_t)b * NIND + c) * SEQLEN + l]
                       : pos[(size_t)(c - NIND) * SEQLEN + l];
}

// ---------------- generic fp32 GEMM: C[b] = A(MxK) @ B[b](KxN) (+R[b]) (+gelu) ----------------
// M%64==0, N%64==0, K%16==0. A shared across batch (weights).
template <int ACT, bool HAS_RES>
__global__ __launch_bounds__(256) void gemm_k(const float* __restrict__ A,
                                              const float* __restrict__ Bm,
                                              const float* __restrict__ Rm,
                                              float* __restrict__ Cm,
                                              int M, int N, int K) {
  __shared__ float As[16][68];
  __shared__ float Bs[16][68];
  int bz = blockIdx.z;
  const float* Bb = Bm + (size_t)bz * K * N;
  float* Cb = Cm + (size_t)bz * M * N;
  const float* Rb = HAS_RES ? (Rm + (size_t)bz * M * N) : nullptr;
  int m0 = blockIdx.y * 64, n0 = blockIdx.x * 64;
  int t = threadIdx.x;
  int tx = t & 15, ty = t >> 4;
  int mA = t >> 2, kA = (t & 3) << 2;
  int kB = t >> 4, nB = (t & 15) << 2;
  float acc[4][4] = {};
  for (int k0 = 0; k0 < K; k0 += 16) {
    float4 av = *(const float4*)(A + (size_t)(m0 + mA) * K + k0 + kA);
    float4 bv = *(const float4*)(Bb + (size_t)(k0 + kB) * N + n0 + nB);
    As[kA + 0][mA] = av.x;
    As[kA + 1][mA] = av.y;
    As[kA + 2][mA] = av.z;
    As[kA + 3][mA] = av.w;
    *(float4*)&Bs[kB][nB] = bv;
    __syncthreads();
#pragma unroll
    for (int kk = 0; kk < 16; ++kk) {
      float4 a4 = *(const float4*)&As[kk][ty << 2];
      float4 b4 = *(const float4*)&Bs[kk][tx << 2];
      float ar[4] = {a4.x, a4.y, a4.z, a4.w};
      float br[4] = {b4.x, b4.y, b4.z, b4.w};
#pragma unroll
      for (int i = 0; i < 4; ++i)
#pragma unroll
        for (int jj = 0; jj < 4; ++jj) acc[i][jj] += ar[i] * br[jj];
    }
    __syncthreads();
  }
#pragma unroll
  for (int i = 0; i < 4; ++i) {
    int m = m0 + (ty << 2) + i;
    size_t off = (size_t)m * N + n0 + (tx << 2);
    float4 o = make_float4(acc[i][0], acc[i][1], acc[i][2], acc[i][3]);
    if (HAS_RES) {
      float4 rr = *(const float4*)(Rb + off);
      o.x += rr.x; o.y += rr.y; o.z += rr.z; o.w += rr.w;
    }
    if (ACT == 1) {  // exact GELU: x*0.5*(1+erf(x/sqrt(2)))
      o.x = 0.5f * o.x * (1.0f + erff(o.x * 0.70710678118654752440f));
      o.y = 0.5f * o.y * (1.0f + erff(o.y * 0.70710678118654752440f));
      o.z = 0.5f * o.z * (1.0f + erff(o.z * 0.70710678118654752440f));
      o.w = 0.5f * o.w * (1.0f + erff(o.w * 0.70710678118654752440f));
    }
    *(float4*)(Cb + off) = o;
  }
}

// ---------------- per-(b,h,vdim) sum of V over all positions ----------------
__global__ __launch_bounds__(256) void vsum_k(const float* __restrict__ v,
                                              float* __restrict__ vs) {
  int row = blockIdx.x;  // 0 .. B*512-1
  const float* p = v + (size_t)row * SEQLEN;
  float s = 0.f;
  for (int i = threadIdx.x; i < SEQLEN; i += 256) s += p[i];
#pragma unroll
  for (int o = 32; o > 0; o >>= 1) s += __shfl_down(s, o, 64);
  __shared__ float red[4];
  if ((threadIdx.x & 63) == 0) red[threadIdx.x >> 6] = s;
  __syncthreads();
  if (threadIdx.x == 0) vs[row] = (red[0] + red[1]) + (red[2] + red[3]);
}

// ---------------- banded attention ----------------
// Per block: (b, h, 64-row l-tile). Window of 192 m-columns [l0-64, l0+128).
// softmax over full 2048 row: out-of-band entries contribute exp(0-m).
// out[v,l] = sum_inband ((e^{s-m}-e^{-m})/Z) * V[v,m] + (e^{-m}/Z) * sum_all V[v,:]
__global__ __launch_bounds__(256) void attn_k(const float* __restrict__ q,
                                              const float* __restrict__ k,
                                              const float* __restrict__ v,
                                              const float* __restrict__ vsum,
                                              float* __restrict__ out) {
  __shared__ float Qs[64][QPITCH];
  __shared__ float KV[(64 * KPITCH > WINW * VPITCH) ? 64 * KPITCH : WINW * VPITCH];
  __shared__ float Pt[WINW][VPITCH];   // P transposed: Pt[c][r]
  __shared__ float rowcoef[64];

  int bz = blockIdx.z, hh = blockIdx.y;
  int l0 = blockIdx.x * 64;
  size_t bh = ((size_t)bz * (NH * NDE) + hh * NDE) * SEQLEN;
  const float* Qp = q + bh;
  const float* Kp = k + bh;
  const float* Vp = v + bh;
  const float* VS = vsum + bz * (NH * NDV) + hh * NDV;
  float* Op = out + bh;

  int t = threadIdx.x;

  // stage Q tile (Qs[d][r]) and K window (KV[d*KPITCH + c])
  for (int idx = t; idx < 64 * 64; idx += 256) {
    int d = idx >> 6, r = idx & 63;
    Qs[d][r] = Qp[(size_t)d * SEQLEN + l0 + r];
  }
  for (int idx = t; idx < 64 * WINW; idx += 256) {
    int d = idx / WINW, c = idx - d * WINW;
    int m = l0 - NREC + c;
    KV[d * KPITCH + c] = (m >= 0 && m < SEQLEN) ? Kp[(size_t)d * SEQLEN + m] : 0.0f;
  }
  __syncthreads();

  // scores: 4x12 micro-tile per thread
  int r0 = (t >> 4) << 2;   // 0..60
  int c0 = (t & 15) * 12;   // 0..180
  float s[4][12];
#pragma unroll
  for (int i = 0; i < 4; ++i)
#pragma unroll
    for (int jj = 0; jj < 12; ++jj) s[i][jj] = 0.f;
  for (int d = 0; d < 64; ++d) {
    float4 a4 = *(const float4*)&Qs[d][r0];
    float ar[4] = {a4.x, a4.y, a4.z, a4.w};
    float4 b0 = *(const float4*)&KV[d * KPITCH + c0];
    float4 b1 = *(const float4*)&KV[d * KPITCH + c0 + 4];
    float4 b2 = *(const float4*)&KV[d * KPITCH + c0 + 8];
    float br[12] = {b0.x, b0.y, b0.z, b0.w, b1.x, b1.y, b1.z, b1.w,
                    b2.x, b2.y, b2.z, b2.w};
#pragma unroll
    for (int i = 0; i < 4; ++i)
#pragma unroll
      for (int jj = 0; jj < 12; ++jj) s[i][jj] += ar[i] * br[jj];
  }

  // per-row softmax stats (16 lanes own each 4-row group; reduce over lanes)
#pragma unroll
  for (int i = 0; i < 4; ++i) {
    int rr = r0 + i;
    int l = l0 + rr;
    float mx = -1e30f;
    bool ib[12];
#pragma unroll
    for (int jj = 0; jj < 12; ++jj) {
      int c = c0 + jj;
      int m = l0 - NREC + c;
      ib[jj] = (c >= rr) && (c <= rr + 2 * NREC) && (m >= 0) && (m < SEQLEN);
      float sv = s[i][jj] * 0.125f;   // 1/sqrt(64)
      s[i][jj] = sv;
      if (ib[jj]) mx = fmaxf(mx, sv);
    }
    mx = fmaxf(mx, __shfl_xor(mx, 1, 64));
    mx = fmaxf(mx, __shfl_xor(mx, 2, 64));
    mx = fmaxf(mx, __shfl_xor(mx, 4, 64));
    mx = fmaxf(mx, __shfl_xor(mx, 8, 64));
    float mrow = fmaxf(mx, 0.0f);     // out-of-band zeros participate in max
    float e0 = expf(-mrow);
    float zs = 0.f;
#pragma unroll
    for (int jj = 0; jj < 12; ++jj) {
      float e = ib[jj] ? expf(s[i][jj] - mrow) : 0.0f;
      s[i][jj] = e;
      zs += e;
    }
    zs += __shfl_xor(zs, 1, 64);
    zs += __shfl_xor(zs, 2, 64);
    zs += __shfl_xor(zs, 4, 64);
    zs += __shfl_xor(zs, 8, 64);
    int lo = l - NREC; if (lo < 0) lo = 0;
    int hi = l + NREC; if (hi > SEQLEN - 1) hi = SEQLEN - 1;
    float Z = zs + (float)(SEQLEN - (hi - lo + 1)) * e0;
    float inv = 1.0f / Z;
#pragma unroll
    for (int jj = 0; jj < 12; ++jj)
      Pt[c0 + jj][rr] = ib[jj] ? (s[i][jj] - e0) * inv : 0.0f;
    if ((t & 15) == 0) rowcoef[rr] = e0 * inv;
  }
  __syncthreads();

  // stage V window transposed: KV[c*VPITCH + d] = V[d][m]
  for (int idx = t; idx < 64 * WINW; idx += 256) {
    int d = idx / WINW, c = idx - d * WINW;
    int m = l0 - NREC + c;
    KV[c * VPITCH + d] = (m >= 0 && m < SEQLEN) ? Vp[(size_t)d * SEQLEN + m] : 0.0f;
  }
  __syncthreads();

  // PV: O[v][l] = sum_c Pt[c][r] * Vt[c][v]  (4x4 micro-tile)
  int rO = (t >> 4) << 2;
  int vO = (t & 15) << 2;
  float acc[4][4] = {};
  for (int c = 0; c < WINW; ++c) {
    float4 p4 = *(const float4*)&Pt[c][rO];
    float4 v4 = *(const float4*)&KV[c * VPITCH + vO];
    float pr[4] = {p4.x, p4.y, p4.z, p4.w};
    float vr[4] = {v4.x, v4.y, v4.z, v4.w};
#pragma unroll
    for (int i = 0; i < 4; ++i)
#pragma unroll
      for (int jj = 0; jj < 4; ++jj) acc[i][jj] += pr[i] * vr[jj];
  }
#pragma unroll
  for (int jj = 0; jj < 4; ++jj) {
    int vd = vO + jj;
    float vsv = VS[vd];
#pragma unroll
    for (int i = 0; i < 4; ++i)
      Op[(size_t)vd * SEQLEN + l0 + rO + i] = acc[i][jj] + rowcoef[rO + i] * vsv;
  }
}

// ---------------- layernorm over channel dim (64) per (b,l) ----------------
__global__ __launch_bounds__(256) void ln_k(const float* __restrict__ in,
                                            float* __restrict__ out,
                                            const float* __restrict__ g,
                                            const float* __restrict__ be) {
  int idx = blockIdx.x * 256 + threadIdx.x;   // < B*SEQLEN
  int b = idx >> 11;
  int l = idx & (SEQLEN - 1);
  const float* base = in + (size_t)b * NDV * SEQLEN + l;
  float* ob = out + (size_t)b * NDV * SEQLEN + l;
  float mu = 0.f, s2 = 0.f;
#pragma unroll
  for (int c = 0; c < NDV; ++c) {
    float xv = base[(size_t)c * SEQLEN];
    mu += xv;
    s2 += xv * xv;
  }
  mu *= (1.0f / NDV);
  float var = s2 * (1.0f / NDV) - mu * mu;
  float rstd = rsqrtf(var + 1e-5f);
#pragma unroll
  for (int c = 0; c < NDV; ++c) {
    float xv = base[(size_t)c * SEQLEN];
    ob[(size_t)c * SEQLEN] = (xv - mu) * rstd * g[c] + be[c];
  }
}

extern "C" void kernel_launch(void* const* d_in, const int* in_sizes, int n_in,
                              void* d_out, int out_size, void* d_ws, size_t ws_size,
                              hipStream_t stream) {
  const float* x    = (const float*)d_in[0];
  const float* Wq   = (const float*)d_in[1];
  const float* Wk   = (const float*)d_in[2];
  const float* Wv   = (const float*)d_in[3];
  const float* Wres = (const float*)d_in[4];
  const float* Wc   = (const float*)d_in[5];
  const float* ln1g = (const float*)d_in[6];
  const float* ln1b = (const float*)d_in[7];
  const float* W1   = (const float*)d_in[8];
  const float* W2   = (const float*)d_in[9];
  const float* ln2g = (const float*)d_in[10];
  const float* ln2b = (const float*)d_in[11];

  float* ws = (float*)d_ws;
  float* pos   = ws;                  // 256*2048        = 524288
  float* xp    = pos + 524288;        // 2*512*2048      = 2097152 (later reused as attnout)
  float* qb    = xp + 2097152;        // 2097152         (later reused as h: 2*256*2048)
  float* kb    = qb + 2097152;        // 2097152         (later reused as pred2)
  float* vb    = kb + 2097152;        // 2097152
  float* vsum  = vb + 2097152;        // 1024
  float* resid = vsum + 1024;         // 2*64*2048       = 262144
  float* pred  = resid + 262144;      // 262144
  float* attnout = xp;                // alias: xp dead after V projection
  float* hbuf    = qb;                // alias: q dead after attention
  float* pred2   = kb;                // alias: k dead after attention
  float* outp  = (float*)d_out;

  pos_k<<<256, 256, 0, stream>>>(pos);
  concat_k<<<(NBATCH * NCIN * SEQLEN) / 256, 256, 0, stream>>>(x, pos, xp);

  dim3 gqkv(32, 8, NBATCH);
  gemm_k<0, false><<<gqkv, 256, 0, stream>>>(Wq, xp, nullptr, qb, 512, SEQLEN, 512);
  gemm_k<0, false><<<gqkv, 256, 0, stream>>>(Wk, xp, nullptr, kb, 512, SEQLEN, 512);
  gemm_k<0, false><<<gqkv, 256, 0, stream>>>(Wv, xp, nullptr, vb, 512, SEQLEN, 512);
  gemm_k<0, false><<<dim3(32, 1, NBATCH), 256, 0, stream>>>(Wres, x, nullptr, resid, 64, SEQLEN, 256);

  vsum_k<<<NBATCH * NH * NDV, 256, 0, stream>>>(vb, vsum);
  attn_k<<<dim3(32, NH, NBATCH), 256, 0, stream>>>(qb, kb, vb, vsum, attnout);

  gemm_k<0, true><<<dim3(32, 1, NBATCH), 256, 0, stream>>>(Wc, attnout, resid, pred, 64, SEQLEN, 512);
  ln_k<<<(NBATCH * SEQLEN) / 256, 256, 0, stream>>>(pred, pred, ln1g, ln1b);
  gemm_k<1, false><<<dim3(32, 4, NBATCH), 256, 0, stream>>>(W1, pred, nullptr, hbuf, 256, SEQLEN, 64);
  gemm_k<0, true><<<dim3(32, 1, NBATCH), 256, 0, stream>>>(W2, hbuf, pred, pred2, 64, SEQLEN, 256);
  ln_k<<<(NBATCH * SEQLEN) / 256, 256, 0, stream>>>(pred2, outp, ln2g, ln2b);
}

// Round 2
// 137.961 us; speedup vs baseline: 2.1414x; 2.1414x over previous
//
#include <hip/hip_runtime.h>
#include <cstdint>
#include <cstddef>

// ---- problem constants ----
#define SEQLEN 2048
#define NBATCH 2
#define NIND   256
#define NPOS   256
#define NCIN   512
#define NH     8
#define NDE    64
#define NDV    64
#define NREC   64

typedef __attribute__((ext_vector_type(8))) short s16x8;
typedef __attribute__((ext_vector_type(4))) float f32x4;

__device__ __forceinline__ unsigned short f2bf(float f) {
  union { float f; unsigned u; } v; v.f = f;
  unsigned r = v.u + 0x7fffu + ((v.u >> 16) & 1u);
  return (unsigned short)(r >> 16);
}
__device__ __forceinline__ float bf2f(unsigned short u) {
  union { unsigned u; float f; } v; v.u = ((unsigned)u) << 16;
  return v.f;
}

// ---------------- positional embedding (exact fp32 chain) ----------------
__global__ __launch_bounds__(256) void pos_k(float* __restrict__ pos) {
  int j = blockIdx.x;
  int i = (j < NPOS / 2) ? j : j - NPOS / 2;
  const double base = (double)1.2f;
  double p = 1.0;
  for (int tt = 0; tt <= i; ++tt) p *= base;
  float w = 0.8f + (float)p;
  float swl = (float)SEQLEN / w;
  const float two_pi = (float)(2.0 * 3.14159265358979323846);
  for (int l = threadIdx.x; l < SEQLEN; l += blockDim.x) {
    float arg = (two_pi * (float)l) / swl;
    pos[(size_t)j * SEQLEN + l] = (j < NPOS / 2) ? sinf(arg) : cosf(arg);
  }
}

// ---------------- transpose-concat: xp_t[b][l][c] bf16 ----------------
__global__ __launch_bounds__(256) void concat_t_k(const float* __restrict__ x,
                                                  const float* __restrict__ pos,
                                                  unsigned short* __restrict__ xpt) {
  __shared__ float tile[64][65];
  int b = blockIdx.z, c0 = blockIdx.y * 64, l0 = blockIdx.x * 64;
  const float* src = (c0 < NIND) ? (x + ((size_t)b * NIND + c0) * SEQLEN)
                                 : (pos + (size_t)(c0 - NIND) * SEQLEN);
  int t = threadIdx.x;
  int ll = t & 63, cq = t >> 6;
#pragma unroll
  for (int i = 0; i < 16; ++i) {
    int cl = cq * 16 + i;
    tile[cl][ll] = src[(size_t)cl * SEQLEN + l0 + ll];
  }
  __syncthreads();
  int cl2 = t & 63, lq = t >> 6;
  unsigned short* dst = xpt + ((size_t)b * SEQLEN + l0) * NCIN + c0;
#pragma unroll
  for (int i = 0; i < 16; ++i) {
    int l = lq * 16 + i;
    dst[(size_t)l * NCIN + cl2] = f2bf(tile[cl2][l]);
  }
}

// ---------------- fp32 -> bf16 convert ----------------
__global__ __launch_bounds__(256) void cvt_k(const float* __restrict__ in,
                                             unsigned short* __restrict__ out, int n4) {
  int i = blockIdx.x * 256 + threadIdx.x;
  if (i >= n4) return;
  float4 v = ((const float4*)in)[i];
  ushort4 o = make_ushort4(f2bf(v.x), f2bf(v.y), f2bf(v.z), f2bf(v.w));
  ((ushort4*)out)[i] = o;
}

// ---------------- fused QKV MFMA GEMM (bf16 in/out, fp32 accum) ----------------
// C[m][n] = sum_k W[m][k] * xp_t[n][k].  128x128 tile, BK=32, 4 waves.
__global__ __launch_bounds__(256) void qkv_gemm_k(const unsigned short* __restrict__ Wqb,
                                                  const unsigned short* __restrict__ Wkb,
                                                  const unsigned short* __restrict__ Wvb,
                                                  const unsigned short* __restrict__ xpt,
                                                  unsigned short* __restrict__ qb,
                                                  unsigned short* __restrict__ kb,
                                                  unsigned short* __restrict__ vb) {
  __shared__ alignas(16) unsigned short Al[128][40];
  __shared__ alignas(16) unsigned short Bl[128][40];
  int bz = blockIdx.z;
  int ysel = blockIdx.y >> 2;
  const unsigned short* W = (ysel == 0) ? Wqb : ((ysel == 1) ? Wkb : Wvb);
  unsigned short* C = (ysel == 0) ? qb : ((ysel == 1) ? kb : vb);
  int m0 = (blockIdx.y & 3) * 128;
  int n0 = blockIdx.x * 128;
  const unsigned short* Bg = xpt + (size_t)bz * SEQLEN * NCIN;
  C += (size_t)bz * 512 * SEQLEN;

  int t = threadIdx.x;
  int w = t >> 6, lane = t & 63, lr = lane & 15, hi = lane >> 4;
  int wm = w >> 1, wn = w & 1;
  int srow = t >> 2, sch = (t & 3) * 8;

  f32x4 acc[4][4];
#pragma unroll
  for (int i = 0; i < 4; ++i)
#pragma unroll
    for (int j = 0; j < 4; ++j) acc[i][j] = (f32x4){0.f, 0.f, 0.f, 0.f};

  for (int k0 = 0; k0 < 512; k0 += 32) {
    int4 a0 = *(const int4*)(W  + (size_t)(m0 + srow)      * 512 + k0 + sch);
    int4 a1 = *(const int4*)(W  + (size_t)(m0 + srow + 64) * 512 + k0 + sch);
    int4 b0 = *(const int4*)(Bg + (size_t)(n0 + srow)      * 512 + k0 + sch);
    int4 b1 = *(const int4*)(Bg + (size_t)(n0 + srow + 64) * 512 + k0 + sch);
    __syncthreads();
    *(int4*)&Al[srow][sch]      = a0;
    *(int4*)&Al[srow + 64][sch] = a1;
    *(int4*)&Bl[srow][sch]      = b0;
    *(int4*)&Bl[srow + 64][sch] = b1;
    __syncthreads();
    s16x8 af[4], bfv[4];
#pragma unroll
    for (int mt = 0; mt < 4; ++mt) af[mt]  = *(const s16x8*)&Al[64 * wm + 16 * mt + lr][8 * hi];
#pragma unroll
    for (int nt = 0; nt < 4; ++nt) bfv[nt] = *(const s16x8*)&Bl[64 * wn + 16 * nt + lr][8 * hi];
#pragma unroll
    for (int mt = 0; mt < 4; ++mt)
#pragma unroll
      for (int nt = 0; nt < 4; ++nt)
        acc[mt][nt] = __builtin_amdgcn_mfma_f32_16x16x32_bf16(af[mt], bfv[nt], acc[mt][nt], 0, 0, 0);
  }
#pragma unroll
  for (int mt = 0; mt < 4; ++mt)
#pragma unroll
    for (int nt = 0; nt < 4; ++nt) {
      int n = n0 + 64 * wn + 16 * nt + lr;
#pragma unroll
      for (int reg = 0; reg < 4; ++reg) {
        int m = m0 + 64 * wm + 16 * mt + 4 * hi + reg;
        C[(size_t)m * SEQLEN + n] = f2bf(acc[mt][nt][reg]);
      }
    }
}

// ---------------- generic fp32 GEMM (small mats): C[b]=A@B[b](+R)(+gelu) ----------------
template <int ACT, bool HAS_RES>
__global__ __launch_bounds__(256) void gemm_k(const float* __restrict__ A,
                                              const float* __restrict__ Bm,
                                              const float* __restrict__ Rm,
                                              float* __restrict__ Cm,
                                              int M, int N, int K) {
  __shared__ float As[16][68];
  __shared__ float Bs[16][68];
  int bz = blockIdx.z;
  const float* Bb = Bm + (size_t)bz * K * N;
  float* Cb = Cm + (size_t)bz * M * N;
  const float* Rb = HAS_RES ? (Rm + (size_t)bz * M * N) : nullptr;
  int m0 = blockIdx.y * 64, n0 = blockIdx.x * 64;
  int t = threadIdx.x;
  int tx = t & 15, ty = t >> 4;
  int mA = t >> 2, kA = (t & 3) << 2;
  int kB = t >> 4, nB = (t & 15) << 2;
  float acc[4][4] = {};
  for (int k0 = 0; k0 < K; k0 += 16) {
    float4 av = *(const float4*)(A + (size_t)(m0 + mA) * K + k0 + kA);
    float4 bv = *(const float4*)(Bb + (size_t)(k0 + kB) * N + n0 + nB);
    As[kA + 0][mA] = av.x;
    As[kA + 1][mA] = av.y;
    As[kA + 2][mA] = av.z;
    As[kA + 3][mA] = av.w;
    *(float4*)&Bs[kB][nB] = bv;
    __syncthreads();
#pragma unroll
    for (int kk = 0; kk < 16; ++kk) {
      float4 a4 = *(const float4*)&As[kk][ty << 2];
      float4 b4 = *(const float4*)&Bs[kk][tx << 2];
      float ar[4] = {a4.x, a4.y, a4.z, a4.w};
      float br[4] = {b4.x, b4.y, b4.z, b4.w};
#pragma unroll
      for (int i = 0; i < 4; ++i)
#pragma unroll
        for (int jj = 0; jj < 4; ++jj) acc[i][jj] += ar[i] * br[jj];
    }
    __syncthreads();
  }
#pragma unroll
  for (int i = 0; i < 4; ++i) {
    int m = m0 + (ty << 2) + i;
    size_t off = (size_t)m * N + n0 + (tx << 2);
    float4 o = make_float4(acc[i][0], acc[i][1], acc[i][2], acc[i][3]);
    if (HAS_RES) {
      float4 rr = *(const float4*)(Rb + off);
      o.x += rr.x; o.y += rr.y; o.z += rr.z; o.w += rr.w;
    }
    if (ACT == 1) {
      o.x = 0.5f * o.x * (1.0f + erff(o.x * 0.70710678118654752440f));
      o.y = 0.5f * o.y * (1.0f + erff(o.y * 0.70710678118654752440f));
      o.z = 0.5f * o.z * (1.0f + erff(o.z * 0.70710678118654752440f));
      o.w = 0.5f * o.w * (1.0f + erff(o.w * 0.70710678118654752440f));
    }
    *(float4*)(Cb + off) = o;
  }
}

// ---------------- V rowsum (bf16 in, fp32 out) ----------------
__global__ __launch_bounds__(256) void vsum_k(const unsigned short* __restrict__ v,
                                              float* __restrict__ vs) {
  int row = blockIdx.x;
  const unsigned short* p = v + (size_t)row * SEQLEN;
  int t = threadIdx.x;
  union { int4 i4; unsigned short s[8]; } u;
  u.i4 = *(const int4*)(p + t * 8);
  float s = 0.f;
#pragma unroll
  for (int j = 0; j < 8; ++j) s += bf2f(u.s[j]);
#pragma unroll
  for (int o = 32; o > 0; o >>= 1) s += __shfl_down(s, o, 64);
  __shared__ float red[4];
  if ((t & 63) == 0) red[t >> 6] = s;
  __syncthreads();
  if (t == 0) vs[row] = (red[0] + red[1]) + (red[2] + red[3]);
}

// ---------------- banded attention, MFMA ----------------
// Block = (b,h,64-row l-tile), 4 waves. Window c in [0,192), m = l0-64+c.
__global__ __launch_bounds__(256) void attn_k(const unsigned short* __restrict__ q,
                                              const unsigned short* __restrict__ k,
                                              const unsigned short* __restrict__ v,
                                              const float* __restrict__ vsum,
                                              float* __restrict__ out) {
  __shared__ alignas(16) unsigned short Qs[64][72];      // Q^T tile [r][d]
  __shared__ alignas(16) unsigned short KtP[13824];      // Kt[c][d] p72; then P[r][c] p200
  __shared__ alignas(16) unsigned short Vs[64][200];     // V tile [v][c]
  __shared__ float rowcoef[64];

  int bz = blockIdx.z, hh = blockIdx.y;
  int l0 = blockIdx.x * 64;
  size_t bh = ((size_t)bz * 512 + hh * 64) * SEQLEN;
  const unsigned short* Qp = q + bh;
  const unsigned short* Kp = k + bh;
  const unsigned short* Vp = v + bh;
  float* Op = out + bh;
  int vsbase = bz * 512 + hh * 64;

  int t = threadIdx.x;
  int w = t >> 6, lane = t & 63, lr = lane & 15, hi = lane >> 4;

  for (int i = t; i < 4096; i += 256) {          // Q transpose stage
    int d = i >> 6, r = i & 63;
    Qs[r][d] = Qp[(size_t)d * SEQLEN + l0 + r];
  }
  for (int i = t; i < 1536; i += 256) {          // K transpose stage
    int d = i / 24, c8 = i - d * 24;
    int m8 = l0 - 64 + c8 * 8;
    union { int4 i4; unsigned short s[8]; } u;
    u.i4 = make_int4(0, 0, 0, 0);
    if (m8 >= 0 && m8 < SEQLEN) u.i4 = *(const int4*)(Kp + (size_t)d * SEQLEN + m8);
#pragma unroll
    for (int jj = 0; jj < 8; ++jj) KtP[(c8 * 8 + jj) * 72 + d] = u.s[jj];
  }
  for (int i = t; i < 1536; i += 256) {          // V stage (no transpose)
    int vd = i / 24, c8 = i - vd * 24;
    int m8 = l0 - 64 + c8 * 8;
    int4 val = make_int4(0, 0, 0, 0);
    if (m8 >= 0 && m8 < SEQLEN) val = *(const int4*)(Vp + (size_t)vd * SEQLEN + m8);
    *(int4*)&Vs[vd][c8 * 8] = val;
  }
  __syncthreads();

  // QK^T: wave w owns rows [16w,16w+16); 12 col tiles x 2 k-steps
  s16x8 a0 = *(const s16x8*)&Qs[16 * w + lr][8 * hi];
  s16x8 a1 = *(const s16x8*)&Qs[16 * w + lr][32 + 8 * hi];
  f32x4 sc[12];
#pragma unroll
  for (int ct = 0; ct < 12; ++ct) {
    s16x8 b0 = *(const s16x8*)&KtP[(16 * ct + lr) * 72 + 8 * hi];
    s16x8 b1 = *(const s16x8*)&KtP[(16 * ct + lr) * 72 + 32 + 8 * hi];
    f32x4 acc = {0.f, 0.f, 0.f, 0.f};
    acc = __builtin_amdgcn_mfma_f32_16x16x32_bf16(a0, b0, acc, 0, 0, 0);
    acc = __builtin_amdgcn_mfma_f32_16x16x32_bf16(a1, b1, acc, 0, 0, 0);
    sc[ct] = acc;
  }

  // register softmax; full-row Z includes (2048-band)*e^{-mx} from zero scores
  float rcv[4];
#pragma unroll
  for (int i = 0; i < 4; ++i) {
    int r = 16 * w + 4 * hi + i;
    int l = l0 + r;
    float mx = 0.0f;                        // out-of-band zeros join the max
    float sv[12];
#pragma unroll
    for (int ct = 0; ct < 12; ++ct) {
      int c = 16 * ct + lr;
      int m = l0 - 64 + c;
      bool ib = (c >= r) && (c <= r + 128) && (m >= 0) && (m < SEQLEN);
      float s = sc[ct][i] * 0.125f;
      sv[ct] = ib ? s : -1e30f;
      mx = ib ? fmaxf(mx, s) : mx;
    }
    mx = fmaxf(mx, __shfl_xor(mx, 1, 64));
    mx = fmaxf(mx, __shfl_xor(mx, 2, 64));
    mx = fmaxf(mx, __shfl_xor(mx, 4, 64));
    mx = fmaxf(mx, __shfl_xor(mx, 8, 64));
    float e0 = expf(-mx);
    float zs = 0.f;
#pragma unroll
    for (int ct = 0; ct < 12; ++ct) {
      float e = (sv[ct] > -1e29f) ? expf(sv[ct] - mx) : 0.0f;
      sv[ct] = e;
      zs += e;
    }
    zs += __shfl_xor(zs, 1, 64);
    zs += __shfl_xor(zs, 2, 64);
    zs += __shfl_xor(zs, 4, 64);
    zs += __shfl_xor(zs, 8, 64);
    int lo = l - NREC; if (lo < 0) lo = 0;
    int hi2 = l + NREC; if (hi2 > SEQLEN - 1) hi2 = SEQLEN - 1;
    float inv = 1.0f / (zs + (float)(SEQLEN - (hi2 - lo + 1)) * e0);
    rcv[i] = e0 * inv;
#pragma unroll
    for (int ct = 0; ct < 12; ++ct)
      sc[ct][i] = (sv[ct] > 0.0f) ? (sv[ct] - e0) * inv : 0.0f;
  }
  __syncthreads();   // all Kt reads drained -> safe to overwrite with P

#pragma unroll
  for (int i = 0; i < 4; ++i) {
    int r = 16 * w + 4 * hi + i;
#pragma unroll
    for (int ct = 0; ct < 12; ++ct)
      KtP[r * 200 + 16 * ct + lr] = f2bf(sc[ct][i]);
  }
  if (lr == 0) {
#pragma unroll
    for (int i = 0; i < 4; ++i) rowcoef[16 * w + 4 * hi + i] = rcv[i];
  }
  __syncthreads();

  // PV as O^T = V * P^T: wave w owns v-rows [16w,16w+16); coalesced stores along l
  s16x8 av[6];
#pragma unroll
  for (int ks = 0; ks < 6; ++ks)
    av[ks] = *(const s16x8*)&Vs[16 * w + lr][32 * ks + 8 * hi];
  float vsv[4];
#pragma unroll
  for (int reg = 0; reg < 4; ++reg) vsv[reg] = vsum[vsbase + 16 * w + 4 * hi + reg];
#pragma unroll
  for (int nt = 0; nt < 4; ++nt) {
    f32x4 acc = {0.f, 0.f, 0.f, 0.f};
#pragma unroll
    for (int ks = 0; ks < 6; ++ks) {
      s16x8 b = *(const s16x8*)&KtP[(16 * nt + lr) * 200 + 32 * ks + 8 * hi];
      acc = __builtin_amdgcn_mfma_f32_16x16x32_bf16(av[ks], b, acc, 0, 0, 0);
    }
    int rcol = 16 * nt + lr;
    float rcf = rowcoef[rcol];
#pragma unroll
    for (int reg = 0; reg < 4; ++reg) {
      int vd = 16 * w + 4 * hi + reg;
      Op[(size_t)vd * SEQLEN + l0 + rcol] = acc[reg] + rcf * vsv[reg];
    }
  }
}

// ---------------- layernorm over channel dim (64) per (b,l) ----------------
__global__ __launch_bounds__(256) void ln_k(const float* __restrict__ in,
                                            float* __restrict__ out,
                                            const float* __restrict__ g,
                                            const float* __restrict__ be) {
  int idx = blockIdx.x * 256 + threadIdx.x;
  int b = idx >> 11;
  int l = idx & (SEQLEN - 1);
  const float* base = in + (size_t)b * NDV * SEQLEN + l;
  float* ob = out + (size_t)b * NDV * SEQLEN + l;
  float mu = 0.f, s2 = 0.f;
#pragma unroll
  for (int c = 0; c < NDV; ++c) {
    float xv = base[(size_t)c * SEQLEN];
    mu += xv;
    s2 += xv * xv;
  }
  mu *= (1.0f / NDV);
  float var = s2 * (1.0f / NDV) - mu * mu;
  float rstd = rsqrtf(var + 1e-5f);
#pragma unroll
  for (int c = 0; c < NDV; ++c) {
    float xv = base[(size_t)c * SEQLEN];
    ob[(size_t)c * SEQLEN] = (xv - mu) * rstd * g[c] + be[c];
  }
}

extern "C" void kernel_launch(void* const* d_in, const int* in_sizes, int n_in,
                              void* d_out, int out_size, void* d_ws, size_t ws_size,
                              hipStream_t stream) {
  const float* x    = (const float*)d_in[0];
  const float* Wq   = (const float*)d_in[1];
  const float* Wk   = (const float*)d_in[2];
  const float* Wv   = (const float*)d_in[3];
  const float* Wres = (const float*)d_in[4];
  const float* Wc   = (const float*)d_in[5];
  const float* ln1g = (const float*)d_in[6];
  const float* ln1b = (const float*)d_in[7];
  const float* W1   = (const float*)d_in[8];
  const float* W2   = (const float*)d_in[9];
  const float* ln2g = (const float*)d_in[10];
  const float* ln2b = (const float*)d_in[11];

  char* base = (char*)d_ws;
  float* pos = (float*)base;            base += (size_t)524288 * 4;
  unsigned short* xpt = (unsigned short*)base; base += (size_t)2097152 * 2;
  unsigned short* wqb = (unsigned short*)base; base += (size_t)262144 * 2;
  unsigned short* wkb = (unsigned short*)base; base += (size_t)262144 * 2;
  unsigned short* wvb = (unsigned short*)base; base += (size_t)262144 * 2;
  unsigned short* qbb = (unsigned short*)base; base += (size_t)2097152 * 2;
  unsigned short* kbb = (unsigned short*)base; base += (size_t)2097152 * 2;
  unsigned short* vbb = (unsigned short*)base; base += (size_t)2097152 * 2;
  float* vsum    = (float*)base;        base += (size_t)1024 * 4;
  float* resid   = (float*)base;        base += (size_t)262144 * 4;
  float* attnout = (float*)base;        base += (size_t)2097152 * 4;
  float* pred    = (float*)base;        base += (size_t)262144 * 4;
  float* hbuf    = (float*)base;        base += (size_t)1048576 * 4;
  float* pred2   = (float*)base;        base += (size_t)262144 * 4;
  float* outp = (float*)d_out;

  pos_k<<<256, 256, 0, stream>>>(pos);
  concat_t_k<<<dim3(32, 8, NBATCH), 256, 0, stream>>>(x, pos, xpt);
  cvt_k<<<256, 256, 0, stream>>>(Wq, wqb, 65536);
  cvt_k<<<256, 256, 0, stream>>>(Wk, wkb, 65536);
  cvt_k<<<256, 256, 0, stream>>>(Wv, wvb, 65536);

  qkv_gemm_k<<<dim3(16, 12, NBATCH), 256, 0, stream>>>(wqb, wkb, wvb, xpt, qbb, kbb, vbb);
  gemm_k<0, false><<<dim3(32, 1, NBATCH), 256, 0, stream>>>(Wres, x, nullptr, resid, 64, SEQLEN, 256);

  vsum_k<<<1024, 256, 0, stream>>>(vbb, vsum);
  attn_k<<<dim3(32, NH, NBATCH), 256, 0, stream>>>(qbb, kbb, vbb, vsum, attnout);

  gemm_k<0, true><<<dim3(32, 1, NBATCH), 256, 0, stream>>>(Wc, attnout, resid, pred, 64, SEQLEN, 512);
  ln_k<<<(NBATCH * SEQLEN) / 256, 256, 0, stream>>>(pred, pred, ln1g, ln1b);
  gemm_k<1, false><<<dim3(32, 4, NBATCH), 256, 0, stream>>>(W1, pred, nullptr, hbuf, 256, SEQLEN, 64);
  gemm_k<0, true><<<dim3(32, 1, NBATCH), 256, 0, stream>>>(W2, hbuf, pred, pred2, 64, SEQLEN, 256);
  ln_k<<<(NBATCH * SEQLEN) / 256, 256, 0, stream>>>(pred2, outp, ln2g, ln2b);
}

// Round 3
// 89.336 us; speedup vs baseline: 3.3069x; 1.5443x over previous
//
#include <hip/hip_runtime.h>
#include <cstdint>
#include <cstddef>

// ---- problem constants ----
#define SEQLEN 2048
#define NBATCH 2
#define NIND   256
#define NPOS   256
#define NCIN   512
#define NH     8
#define NDE    64
#define NDV    64
#define NREC   64

typedef __attribute__((ext_vector_type(8))) short s16x8;
typedef __attribute__((ext_vector_type(4))) float f32x4;

__device__ __forceinline__ unsigned short f2bf(float f) {
  union { float f; unsigned u; } v; v.f = f;
  unsigned r = v.u + 0x7fffu + ((v.u >> 16) & 1u);
  return (unsigned short)(r >> 16);
}

// ---------------- concat + inline positional embedding -> xp_t[b][l][512] bf16 ----------------
__global__ __launch_bounds__(256) void concat_pos_k(const float* __restrict__ x,
                                                    unsigned short* __restrict__ xpt) {
  int b = blockIdx.z, c0 = blockIdx.y * 64, l0 = blockIdx.x * 64;
  int t = threadIdx.x;
  if (c0 < NIND) {
    // transpose x tile through LDS
    __shared__ float tile[64][65];
    const float* src = x + ((size_t)b * NIND + c0) * SEQLEN;
    int ll = t & 63, cq = t >> 6;
#pragma unroll
    for (int i = 0; i < 16; ++i) {
      int cl = cq * 16 + i;
      tile[cl][ll] = src[(size_t)cl * SEQLEN + l0 + ll];
    }
    __syncthreads();
    int cl2 = t & 63, lq = t >> 6;
    unsigned short* dst = xpt + ((size_t)b * SEQLEN + l0) * NCIN + c0;
#pragma unroll
    for (int i = 0; i < 16; ++i) {
      int l = lq * 16 + i;
      dst[(size_t)l * NCIN + cl2] = f2bf(tile[cl2][l]);
    }
  } else {
    // positional channels computed inline (exact fp32 chain as reference)
    int c = c0 + (t & 63);            // global channel 256..511
    int j = c - NIND;                 // 0..255
    int i = (j < NPOS / 2) ? j : j - NPOS / 2;
    const double base = (double)1.2f;
    double p = 1.0;
    for (int tt = 0; tt <= i; ++tt) p *= base;
    float w = 0.8f + (float)p;
    float swl = (float)SEQLEN / w;
    const float two_pi = (float)(2.0 * 3.14159265358979323846);
    int wv = t >> 6;
    unsigned short* dst = xpt + (size_t)b * SEQLEN * NCIN;
#pragma unroll
    for (int it = 0; it < 16; ++it) {
      int l = l0 + 16 * wv + it;
      float arg = (two_pi * (float)l) / swl;
      float val = (j < NPOS / 2) ? sinf(arg) : cosf(arg);
      dst[(size_t)l * NCIN + c] = f2bf(val);
    }
  }
}

// ---------------- Wq/Wk/Wv fp32->bf16 ----------------
__global__ __launch_bounds__(256) void cvt3_k(const float* __restrict__ wq,
                                              const float* __restrict__ wk,
                                              const float* __restrict__ wv,
                                              unsigned short* __restrict__ oq,
                                              unsigned short* __restrict__ ok,
                                              unsigned short* __restrict__ ov) {
  const float* in = (blockIdx.y == 0) ? wq : ((blockIdx.y == 1) ? wk : wv);
  unsigned short* out = (blockIdx.y == 0) ? oq : ((blockIdx.y == 1) ? ok : ov);
  int i = blockIdx.x * 256 + threadIdx.x;     // < 65536 exactly
  float4 v = ((const float4*)in)[i];
  ((ushort4*)out)[i] = make_ushort4(f2bf(v.x), f2bf(v.y), f2bf(v.z), f2bf(v.w));
}

// ---------------- fused QKV MFMA GEMM ----------------
// Q,K stored transposed [b][h][l][64]; V stored d-major [b][h*64+d][l].
__global__ __launch_bounds__(256) void qkv_gemm_k(const unsigned short* __restrict__ Wqb,
                                                  const unsigned short* __restrict__ Wkb,
                                                  const unsigned short* __restrict__ Wvb,
                                                  const unsigned short* __restrict__ xpt,
                                                  unsigned short* __restrict__ qt,
                                                  unsigned short* __restrict__ kt,
                                                  unsigned short* __restrict__ vb) {
  __shared__ alignas(16) unsigned short Al[128][40];
  __shared__ alignas(16) unsigned short Bl[128][40];
  int bz = blockIdx.z;
  int ysel = blockIdx.y >> 2;
  const unsigned short* W = (ysel == 0) ? Wqb : ((ysel == 1) ? Wkb : Wvb);
  unsigned short* C = (ysel == 0) ? qt : ((ysel == 1) ? kt : vb);
  int m0 = (blockIdx.y & 3) * 128;
  int n0 = blockIdx.x * 128;
  const unsigned short* Bg = xpt + (size_t)bz * SEQLEN * NCIN;
  C += (size_t)bz * 512 * SEQLEN;

  int t = threadIdx.x;
  int w = t >> 6, lane = t & 63, lr = lane & 15, hi = lane >> 4;
  int wm = w >> 1, wn = w & 1;
  int srow = t >> 2, sch = (t & 3) * 8;

  f32x4 acc[4][4];
#pragma unroll
  for (int i = 0; i < 4; ++i)
#pragma unroll
    for (int j = 0; j < 4; ++j) acc[i][j] = (f32x4){0.f, 0.f, 0.f, 0.f};

  for (int k0 = 0; k0 < 512; k0 += 32) {
    int4 a0 = *(const int4*)(W  + (size_t)(m0 + srow)      * 512 + k0 + sch);
    int4 a1 = *(const int4*)(W  + (size_t)(m0 + srow + 64) * 512 + k0 + sch);
    int4 b0 = *(const int4*)(Bg + (size_t)(n0 + srow)      * 512 + k0 + sch);
    int4 b1 = *(const int4*)(Bg + (size_t)(n0 + srow + 64) * 512 + k0 + sch);
    __syncthreads();
    *(int4*)&Al[srow][sch]      = a0;
    *(int4*)&Al[srow + 64][sch] = a1;
    *(int4*)&Bl[srow][sch]      = b0;
    *(int4*)&Bl[srow + 64][sch] = b1;
    __syncthreads();
    s16x8 af[4], bfv[4];
#pragma unroll
    for (int mt = 0; mt < 4; ++mt) af[mt]  = *(const s16x8*)&Al[64 * wm + 16 * mt + lr][8 * hi];
#pragma unroll
    for (int nt = 0; nt < 4; ++nt) bfv[nt] = *(const s16x8*)&Bl[64 * wn + 16 * nt + lr][8 * hi];
#pragma unroll
    for (int mt = 0; mt < 4; ++mt)
#pragma unroll
      for (int nt = 0; nt < 4; ++nt)
        acc[mt][nt] = __builtin_amdgcn_mfma_f32_16x16x32_bf16(af[mt], bfv[nt], acc[mt][nt], 0, 0, 0);
  }
  if (ysel < 2) {
    // transposed store: [h][l][d]
#pragma unroll
    for (int mt = 0; mt < 4; ++mt) {
      int mm = m0 + 64 * wm + 16 * mt;     // multiple of 16
      int h = mm >> 6;
      int d0 = (mm & 63) + 4 * hi;
#pragma unroll
      for (int nt = 0; nt < 4; ++nt) {
        int n = n0 + 64 * wn + 16 * nt + lr;
        ushort4 o = make_ushort4(f2bf(acc[mt][nt][0]), f2bf(acc[mt][nt][1]),
                                 f2bf(acc[mt][nt][2]), f2bf(acc[mt][nt][3]));
        *(ushort4*)&C[((size_t)h * SEQLEN + n) * 64 + d0] = o;
      }
    }
  } else {
#pragma unroll
    for (int mt = 0; mt < 4; ++mt)
#pragma unroll
      for (int nt = 0; nt < 4; ++nt) {
        int n = n0 + 64 * wn + 16 * nt + lr;
#pragma unroll
        for (int reg = 0; reg < 4; ++reg) {
          int m = m0 + 64 * wm + 16 * mt + 4 * hi + reg;
          C[(size_t)m * SEQLEN + n] = f2bf(acc[mt][nt][reg]);
        }
      }
  }
}

// ---------------- V rowsum ----------------
__global__ __launch_bounds__(256) void vsum_k(const unsigned short* __restrict__ v,
                                              float* __restrict__ vs) {
  int row = blockIdx.x;
  const unsigned short* p = v + (size_t)row * SEQLEN;
  int t = threadIdx.x;
  union { int4 i4; unsigned short s[8]; } u;
  u.i4 = *(const int4*)(p + t * 8);
  float s = 0.f;
#pragma unroll
  for (int j = 0; j < 8; ++j) {
    union { unsigned uu; float f; } c; c.uu = ((unsigned)u.s[j]) << 16;
    s += c.f;
  }
#pragma unroll
  for (int o = 32; o > 0; o >>= 1) s += __shfl_down(s, o, 64);
  __shared__ float red[4];
  if ((t & 63) == 0) red[t >> 6] = s;
  __syncthreads();
  if (t == 0) vs[row] = (red[0] + red[1]) + (red[2] + red[3]);
}

// ---------------- banded attention, MFMA, direct-global fragments ----------------
__global__ __launch_bounds__(256) void attn_k(const unsigned short* __restrict__ qt,
                                              const unsigned short* __restrict__ kt,
                                              const unsigned short* __restrict__ vb,
                                              const float* __restrict__ vsum,
                                              unsigned short* __restrict__ attnt) {
  __shared__ alignas(16) unsigned short Ps[64 * 200];
  __shared__ float rowcoef[64];

  int bz = blockIdx.z, hh = blockIdx.y;
  int l0 = blockIdx.x * 64;
  int bh = bz * NH + hh;
  const unsigned short* Qb = qt + (size_t)bh * SEQLEN * 64;
  const unsigned short* Kb = kt + (size_t)bh * SEQLEN * 64;
  const unsigned short* Vp = vb + (size_t)(bz * 512 + hh * 64) * SEQLEN;
  int vsbase = bz * 512 + hh * 64;

  int t = threadIdx.x;
  int w = t >> 6, lane = t & 63, lr = lane & 15, hi = lane >> 4;

  union U { int4 i4; s16x8 v; };

  // Q fragments (rows l0+16w+lr)
  U a0, a1;
  a0.v = *(const s16x8*)(Qb + ((size_t)(l0 + 16 * w + lr)) * 64 + 8 * hi);
  a1.v = *(const s16x8*)(Qb + ((size_t)(l0 + 16 * w + lr)) * 64 + 32 + 8 * hi);

  f32x4 sc[12];
#pragma unroll
  for (int ct = 0; ct < 12; ++ct) {
    int m = l0 - 64 + 16 * ct + lr;
    U b0, b1;
    b0.i4 = make_int4(0, 0, 0, 0);
    b1.i4 = make_int4(0, 0, 0, 0);
    if (m >= 0 && m < SEQLEN) {
      b0.v = *(const s16x8*)(Kb + (size_t)m * 64 + 8 * hi);
      b1.v = *(const s16x8*)(Kb + (size_t)m * 64 + 32 + 8 * hi);
    }
    f32x4 acc = {0.f, 0.f, 0.f, 0.f};
    acc = __builtin_amdgcn_mfma_f32_16x16x32_bf16(a0.v, b0.v, acc, 0, 0, 0);
    acc = __builtin_amdgcn_mfma_f32_16x16x32_bf16(a1.v, b1.v, acc, 0, 0, 0);
    sc[ct] = acc;
  }

  // register softmax; full-row Z includes (2048-band)*e^{-mx} from zero scores
  float rcv[4];
#pragma unroll
  for (int i = 0; i < 4; ++i) {
    int r = 16 * w + 4 * hi + i;
    int l = l0 + r;
    float mx = 0.0f;
    float sv[12];
#pragma unroll
    for (int ct = 0; ct < 12; ++ct) {
      int c = 16 * ct + lr;
      int m = l0 - 64 + c;
      bool ib = (c >= r) && (c <= r + 128) && (m >= 0) && (m < SEQLEN);
      float s = sc[ct][i] * 0.125f;
      sv[ct] = ib ? s : -1e30f;
      mx = ib ? fmaxf(mx, s) : mx;
    }
    mx = fmaxf(mx, __shfl_xor(mx, 1, 64));
    mx = fmaxf(mx, __shfl_xor(mx, 2, 64));
    mx = fmaxf(mx, __shfl_xor(mx, 4, 64));
    mx = fmaxf(mx, __shfl_xor(mx, 8, 64));
    float e0 = expf(-mx);
    float zs = 0.f;
#pragma unroll
    for (int ct = 0; ct < 12; ++ct) {
      float e = (sv[ct] > -1e29f) ? expf(sv[ct] - mx) : 0.0f;
      sv[ct] = e;
      zs += e;
    }
    zs += __shfl_xor(zs, 1, 64);
    zs += __shfl_xor(zs, 2, 64);
    zs += __shfl_xor(zs, 4, 64);
    zs += __shfl_xor(zs, 8, 64);
    int lo = l - NREC; if (lo < 0) lo = 0;
    int hi2 = l + NREC; if (hi2 > SEQLEN - 1) hi2 = SEQLEN - 1;
    float inv = 1.0f / (zs + (float)(SEQLEN - (hi2 - lo + 1)) * e0);
    rcv[i] = e0 * inv;
#pragma unroll
    for (int ct = 0; ct < 12; ++ct)
      sc[ct][i] = (sv[ct] > 0.0f) ? (sv[ct] - e0) * inv : 0.0f;
  }

#pragma unroll
  for (int i = 0; i < 4; ++i) {
    int r = 16 * w + 4 * hi + i;
#pragma unroll
    for (int ct = 0; ct < 12; ++ct)
      Ps[r * 200 + 16 * ct + lr] = f2bf(sc[ct][i]);
  }
  if (lr == 0) {
#pragma unroll
    for (int i = 0; i < 4; ++i) rowcoef[16 * w + 4 * hi + i] = rcv[i];
  }
  __syncthreads();

  // PV as O^T = V * P^T; V fragments direct from global (d-major layout)
  U av[6];
#pragma unroll
  for (int ks = 0; ks < 6; ++ks) {
    int m8 = l0 - 64 + 32 * ks + 8 * hi;
    av[ks].i4 = make_int4(0, 0, 0, 0);
    if (m8 >= 0 && m8 < SEQLEN)
      av[ks].v = *(const s16x8*)(Vp + (size_t)(16 * w + lr) * SEQLEN + m8);
  }
  float vsv[4];
#pragma unroll
  for (int reg = 0; reg < 4; ++reg) vsv[reg] = vsum[vsbase + 16 * w + 4 * hi + reg];

  unsigned short* Ob = attnt + ((size_t)bz * SEQLEN) * 512 + hh * 64;
#pragma unroll
  for (int nt = 0; nt < 4; ++nt) {
    f32x4 acc = {0.f, 0.f, 0.f, 0.f};
#pragma unroll
    for (int ks = 0; ks < 6; ++ks) {
      s16x8 b = *(const s16x8*)&Ps[(16 * nt + lr) * 200 + 32 * ks + 8 * hi];
      acc = __builtin_amdgcn_mfma_f32_16x16x32_bf16(av[ks].v, b, acc, 0, 0, 0);
    }
    int l = l0 + 16 * nt + lr;
    float rcf = rowcoef[16 * nt + lr];
    ushort4 o = make_ushort4(f2bf(acc[0] + rcf * vsv[0]), f2bf(acc[1] + rcf * vsv[1]),
                             f2bf(acc[2] + rcf * vsv[2]), f2bf(acc[3] + rcf * vsv[3]));
    *(ushort4*)&Ob[(size_t)l * 512 + 16 * w + 4 * hi] = o;
  }
}

// ---------------- fused [Wc|Wres] @ [attnout_t|x_t]^T + LN1 ----------------
// M=64, N=2048, K=768. Writes pred fp32 and bf16, layout [b][l][64].
__global__ __launch_bounds__(256) void wc_ln1_k(const float* __restrict__ Wc,
                                                const float* __restrict__ Wres,
                                                const unsigned short* __restrict__ attnt,
                                                const unsigned short* __restrict__ xpt,
                                                const float* __restrict__ g,
                                                const float* __restrict__ be,
                                                float* __restrict__ pred32,
                                                unsigned short* __restrict__ predbf) {
  __shared__ alignas(16) unsigned short Al[64][72];
  __shared__ alignas(16) unsigned short Bl[64][72];
  __shared__ float gs[64], bs[64];
  int b = blockIdx.y, n0 = blockIdx.x * 64;
  int t = threadIdx.x;
  int w = t >> 6, lane = t & 63, lr = lane & 15, hi = lane >> 4;
  int sr = t >> 2, cb = (t & 3) * 16;
  if (t < 64) { gs[t] = g[t]; bs[t] = be[t]; }

  const unsigned short* arow = attnt + ((size_t)b * SEQLEN + n0 + sr) * 512;
  const unsigned short* xrow = xpt + ((size_t)b * SEQLEN + n0 + sr) * 512;

  f32x4 acc[4];
#pragma unroll
  for (int i = 0; i < 4; ++i) acc[i] = (f32x4){0.f, 0.f, 0.f, 0.f};

  for (int k0 = 0; k0 < 768; k0 += 64) {
    // A: Wc (k<512) else Wres
    float4 fa[4];
#pragma unroll
    for (int j = 0; j < 4; ++j) {
      int k = k0 + cb + 4 * j;
      fa[j] = (k < 512) ? *(const float4*)(Wc + (size_t)sr * 512 + k)
                        : *(const float4*)(Wres + (size_t)sr * 256 + (k - 512));
    }
    // B: attnout (k<512) else x channels of xpt
    const unsigned short* bsrc = (k0 < 512) ? (arow + k0 + cb) : (xrow + (k0 - 512) + cb);
    int4 fb0 = *(const int4*)bsrc;
    int4 fb1 = *(const int4*)(bsrc + 8);
    __syncthreads();
#pragma unroll
    for (int j = 0; j < 4; ++j)
      *(ushort4*)&Al[sr][cb + 4 * j] = make_ushort4(f2bf(fa[j].x), f2bf(fa[j].y), f2bf(fa[j].z), f2bf(fa[j].w));
    *(int4*)&Bl[sr][cb] = fb0;
    *(int4*)&Bl[sr][cb + 8] = fb1;
    __syncthreads();
#pragma unroll
    for (int ks = 0; ks < 2; ++ks) {
      s16x8 bf = *(const s16x8*)&Bl[16 * w + lr][32 * ks + 8 * hi];
#pragma unroll
      for (int mt = 0; mt < 4; ++mt) {
        s16x8 af = *(const s16x8*)&Al[16 * mt + lr][32 * ks + 8 * hi];
        acc[mt] = __builtin_amdgcn_mfma_f32_16x16x32_bf16(af, bf, acc[mt], 0, 0, 0);
      }
    }
  }
  // LN over the 64 channels of column l = n0 + 16w + lr
  float sum = 0.f, sq = 0.f;
#pragma unroll
  for (int mt = 0; mt < 4; ++mt)
#pragma unroll
    for (int reg = 0; reg < 4; ++reg) { float v = acc[mt][reg]; sum += v; sq += v * v; }
  sum += __shfl_xor(sum, 16, 64); sq += __shfl_xor(sq, 16, 64);
  sum += __shfl_xor(sum, 32, 64); sq += __shfl_xor(sq, 32, 64);
  float mu = sum * (1.0f / 64.0f);
  float var = sq * (1.0f / 64.0f) - mu * mu;
  float rstd = rsqrtf(var + 1e-5f);
  int l = n0 + 16 * w + lr;
#pragma unroll
  for (int mt = 0; mt < 4; ++mt) {
    float o[4];
#pragma unroll
    for (int reg = 0; reg < 4; ++reg) {
      int m = 16 * mt + 4 * hi + reg;
      o[reg] = (acc[mt][reg] - mu) * rstd * gs[m] + bs[m];
    }
    size_t off = ((size_t)b * SEQLEN + l) * 64 + 16 * mt + 4 * hi;
    *(float4*)&pred32[off] = make_float4(o[0], o[1], o[2], o[3]);
    *(ushort4*)&predbf[off] = make_ushort4(f2bf(o[0]), f2bf(o[1]), f2bf(o[2]), f2bf(o[3]));
  }
}

// ---------------- W1 @ pred^T + exact GELU -> h_t[b][l][256] bf16 ----------------
__global__ __launch_bounds__(256) void w1_k(const float* __restrict__ W1,
                                            const unsigned short* __restrict__ predbf,
                                            unsigned short* __restrict__ ht) {
  __shared__ alignas(16) unsigned short Al[256][72];
  __shared__ alignas(16) unsigned short Bl[64][72];
  int b = blockIdx.y, n0 = blockIdx.x * 64;
  int t = threadIdx.x;
  int w = t >> 6, lane = t & 63, lr = lane & 15, hi = lane >> 4;

  // stage A: W1 row t (64 floats)
#pragma unroll
  for (int j = 0; j < 16; ++j) {
    float4 f = *(const float4*)(W1 + (size_t)t * 64 + 4 * j);
    *(ushort4*)&Al[t][4 * j] = make_ushort4(f2bf(f.x), f2bf(f.y), f2bf(f.z), f2bf(f.w));
  }
  // stage B
  int sr = t >> 2, cb = (t & 3) * 16;
  *(int4*)&Bl[sr][cb] = *(const int4*)(predbf + ((size_t)b * SEQLEN + n0 + sr) * 64 + cb);
  *(int4*)&Bl[sr][cb + 8] = *(const int4*)(predbf + ((size_t)b * SEQLEN + n0 + sr) * 64 + cb + 8);
  __syncthreads();

  s16x8 bf[4][2];
#pragma unroll
  for (int nt = 0; nt < 4; ++nt)
#pragma unroll
    for (int ks = 0; ks < 2; ++ks) bf[nt][ks] = *(const s16x8*)&Bl[16 * nt + lr][32 * ks + 8 * hi];

#pragma unroll
  for (int mt = 0; mt < 4; ++mt) {
    s16x8 a0 = *(const s16x8*)&Al[64 * w + 16 * mt + lr][8 * hi];
    s16x8 a1 = *(const s16x8*)&Al[64 * w + 16 * mt + lr][32 + 8 * hi];
#pragma unroll
    for (int nt = 0; nt < 4; ++nt) {
      f32x4 acc = {0.f, 0.f, 0.f, 0.f};
      acc = __builtin_amdgcn_mfma_f32_16x16x32_bf16(a0, bf[nt][0], acc, 0, 0, 0);
      acc = __builtin_amdgcn_mfma_f32_16x16x32_bf16(a1, bf[nt][1], acc, 0, 0, 0);
      int l = n0 + 16 * nt + lr;
      ushort4 o;
      float v0 = acc[0], v1 = acc[1], v2 = acc[2], v3 = acc[3];
      v0 = 0.5f * v0 * (1.0f + erff(v0 * 0.70710678118654752440f));
      v1 = 0.5f * v1 * (1.0f + erff(v1 * 0.70710678118654752440f));
      v2 = 0.5f * v2 * (1.0f + erff(v2 * 0.70710678118654752440f));
      v3 = 0.5f * v3 * (1.0f + erff(v3 * 0.70710678118654752440f));
      o = make_ushort4(f2bf(v0), f2bf(v1), f2bf(v2), f2bf(v3));
      *(ushort4*)&ht[((size_t)b * SEQLEN + l) * 256 + 64 * w + 16 * mt + 4 * hi] = o;
    }
  }
}

// ---------------- W2 @ h^T + residual + LN2 + transpose-store ----------------
__global__ __launch_bounds__(256) void w2_ln2_k(const float* __restrict__ W2,
                                                const unsigned short* __restrict__ ht,
                                                const float* __restrict__ pred32,
                                                const float* __restrict__ g,
                                                const float* __restrict__ be,
                                                float* __restrict__ outp) {
  __shared__ alignas(16) unsigned short Al[64][72];
  __shared__ alignas(16) unsigned short Bl[64][72];
  __shared__ float gs[64], bs[64];
  int b = blockIdx.y, n0 = blockIdx.x * 64;
  int t = threadIdx.x;
  int w = t >> 6, lane = t & 63, lr = lane & 15, hi = lane >> 4;
  int sr = t >> 2, cb = (t & 3) * 16;
  if (t < 64) { gs[t] = g[t]; bs[t] = be[t]; }

  f32x4 acc[4];
#pragma unroll
  for (int i = 0; i < 4; ++i) acc[i] = (f32x4){0.f, 0.f, 0.f, 0.f};

  for (int k0 = 0; k0 < 256; k0 += 64) {
    float4 fa[4];
#pragma unroll
    for (int j = 0; j < 4; ++j)
      fa[j] = *(const float4*)(W2 + (size_t)sr * 256 + k0 + cb + 4 * j);
    const unsigned short* bsrc = ht + ((size_t)b * SEQLEN + n0 + sr) * 256 + k0 + cb;
    int4 fb0 = *(const int4*)bsrc;
    int4 fb1 = *(const int4*)(bsrc + 8);
    __syncthreads();
#pragma unroll
    for (int j = 0; j < 4; ++j)
      *(ushort4*)&Al[sr][cb + 4 * j] = make_ushort4(f2bf(fa[j].x), f2bf(fa[j].y), f2bf(fa[j].z), f2bf(fa[j].w));
    *(int4*)&Bl[sr][cb] = fb0;
    *(int4*)&Bl[sr][cb + 8] = fb1;
    __syncthreads();
#pragma unroll
    for (int ks = 0; ks < 2; ++ks) {
      s16x8 bf = *(const s16x8*)&Bl[16 * w + lr][32 * ks + 8 * hi];
#pragma unroll
      for (int mt = 0; mt < 4; ++mt) {
        s16x8 af = *(const s16x8*)&Al[16 * mt + lr][32 * ks + 8 * hi];
        acc[mt] = __builtin_amdgcn_mfma_f32_16x16x32_bf16(af, bf, acc[mt], 0, 0, 0);
      }
    }
  }
  int l = n0 + 16 * w + lr;
  // residual add
#pragma unroll
  for (int mt = 0; mt < 4; ++mt) {
    float4 r = *(const float4*)&pred32[((size_t)b * SEQLEN + l) * 64 + 16 * mt + 4 * hi];
    acc[mt][0] += r.x; acc[mt][1] += r.y; acc[mt][2] += r.z; acc[mt][3] += r.w;
  }
  float sum = 0.f, sq = 0.f;
#pragma unroll
  for (int mt = 0; mt < 4; ++mt)
#pragma unroll
    for (int reg = 0; reg < 4; ++reg) { float v = acc[mt][reg]; sum += v; sq += v * v; }
  sum += __shfl_xor(sum, 16, 64); sq += __shfl_xor(sq, 16, 64);
  sum += __shfl_xor(sum, 32, 64); sq += __shfl_xor(sq, 32, 64);
  float mu = sum * (1.0f / 64.0f);
  float var = sq * (1.0f / 64.0f) - mu * mu;
  float rstd = rsqrtf(var + 1e-5f);
  float* ob = outp + (size_t)b * 64 * SEQLEN;
#pragma unroll
  for (int mt = 0; mt < 4; ++mt)
#pragma unroll
    for (int reg = 0; reg < 4; ++reg) {
      int m = 16 * mt + 4 * hi + reg;
      ob[(size_t)m * SEQLEN + l] = (acc[mt][reg] - mu) * rstd * gs[m] + bs[m];
    }
}

extern "C" void kernel_launch(void* const* d_in, const int* in_sizes, int n_in,
                              void* d_out, int out_size, void* d_ws, size_t ws_size,
                              hipStream_t stream) {
  const float* x    = (const float*)d_in[0];
  const float* Wq   = (const float*)d_in[1];
  const float* Wk   = (const float*)d_in[2];
  const float* Wv   = (const float*)d_in[3];
  const float* Wres = (const float*)d_in[4];
  const float* Wc   = (const float*)d_in[5];
  const float* ln1g = (const float*)d_in[6];
  const float* ln1b = (const float*)d_in[7];
  const float* W1   = (const float*)d_in[8];
  const float* W2   = (const float*)d_in[9];
  const float* ln2g = (const float*)d_in[10];
  const float* ln2b = (const float*)d_in[11];

  char* base = (char*)d_ws;
  unsigned short* xpt = (unsigned short*)base; base += (size_t)2097152 * 2;
  unsigned short* wqb = (unsigned short*)base; base += (size_t)262144 * 2;
  unsigned short* wkb = (unsigned short*)base; base += (size_t)262144 * 2;
  unsigned short* wvb = (unsigned short*)base; base += (size_t)262144 * 2;
  unsigned short* qt  = (unsigned short*)base; base += (size_t)2097152 * 2;
  unsigned short* kt  = (unsigned short*)base; base += (size_t)2097152 * 2;
  unsigned short* vbb = (unsigned short*)base; base += (size_t)2097152 * 2;
  float* vsum         = (float*)base;          base += (size_t)1024 * 4;
  unsigned short* attnt = (unsigned short*)base; base += (size_t)2097152 * 2;
  float* pred32       = (float*)base;          base += (size_t)262144 * 4;
  unsigned short* predbf = (unsigned short*)base; base += (size_t)262144 * 2;
  unsigned short* ht  = (unsigned short*)base; base += (size_t)1048576 * 2;
  float* outp = (float*)d_out;

  concat_pos_k<<<dim3(32, 8, NBATCH), 256, 0, stream>>>(x, xpt);
  cvt3_k<<<dim3(256, 3), 256, 0, stream>>>(Wq, Wk, Wv, wqb, wkb, wvb);
  qkv_gemm_k<<<dim3(16, 12, NBATCH), 256, 0, stream>>>(wqb, wkb, wvb, xpt, qt, kt, vbb);
  vsum_k<<<1024, 256, 0, stream>>>(vbb, vsum);
  attn_k<<<dim3(32, NH, NBATCH), 256, 0, stream>>>(qt, kt, vbb, vsum, attnt);
  wc_ln1_k<<<dim3(32, NBATCH), 256, 0, stream>>>(Wc, Wres, attnt, xpt, ln1g, ln1b, pred32, predbf);
  w1_k<<<dim3(32, NBATCH), 256, 0, stream>>>(W1, predbf, ht);
  w2_ln2_k<<<dim3(32, NBATCH), 256, 0, stream>>>(W2, ht, pred32, ln2g, ln2b, outp);
}